// Round 1
// baseline (7018.827 us; speedup 1.0000x reference)
//
#include <hip/hip_runtime.h>
#include <math.h>

#define NS 4096

// LDS layout (floats):
//   xsp : [0, 640)            padded input (612 used); later feat[256]@0, h[128]@256, zsq[128]@384
//   bufA: [640, 640+16384)    p1[64][256], later p3[256][64]
//   bufB: [17024, 17024+16384) p2[128][128]
#define LDS_A_FLOATS (640 + 16384 + 16384)

__global__ __launch_bounds__(512, 2)
void cnn_fused(const float* __restrict__ samples,
               const float* __restrict__ w1, const float* __restrict__ b1,
               const float* __restrict__ w2, const float* __restrict__ b2,
               const float* __restrict__ w3, const float* __restrict__ b3,
               const float* __restrict__ fcw, const float* __restrict__ fcb,
               const float* __restrict__ gamma_, const float* __restrict__ beta_,
               const float* __restrict__ bnm, const float* __restrict__ bnv,
               float* __restrict__ zout, float* __restrict__ sqout)
{
    extern __shared__ float lds[];
    float* xsp  = lds;
    float* bufA = lds + 640;
    float* bufB = lds + 640 + 16384;

    const int n = blockIdx.x;
    const int t = threadIdx.x;

    // ---- stage input with (49,50) zero padding: xsp[idx] = x[idx-49]
    for (int idx = t; idx < 612; idx += 512) {
        int src = idx - 49;
        xsp[idx] = (src >= 0 && src < 512) ? samples[n * 512 + src] : 0.f;
    }
    __syncthreads();

    // ---- conv1 (1->64, k=100) + relu + maxpool2 -> p1[64][256] in bufA
    {
        const int ch = t >> 8;          // 0..1  (wave-uniform) -> channel half
        const int p  = t & 255;         // pooled output position
        const int l0 = 2 * p;
        for (int ccb = 0; ccb < 4; ++ccb) {
            const int cbase = ch * 32 + ccb * 8;
            float a0[8], a1[8];
            #pragma unroll
            for (int cj = 0; cj < 8; ++cj) { a0[cj] = b1[cbase + cj]; a1[cj] = a0[cj]; }
            float xa = xsp[l0];
            #pragma unroll 4
            for (int k = 0; k < 100; ++k) {
                float xb = xsp[l0 + k + 1];
                #pragma unroll
                for (int cj = 0; cj < 8; ++cj) {
                    float wv = w1[(cbase + cj) * 100 + k];   // wave-uniform -> s_load
                    a0[cj] = fmaf(wv, xa, a0[cj]);
                    a1[cj] = fmaf(wv, xb, a1[cj]);
                }
                xa = xb;
            }
            #pragma unroll
            for (int cj = 0; cj < 8; ++cj)
                bufA[(cbase + cj) * 256 + p] = fmaxf(fmaxf(a0[cj], a1[cj]), 0.f);
        }
    }
    __syncthreads();

    // ---- conv2 (64->128, k=5, pad 2) + relu + maxpool2 -> p2[128][128] in bufB
    {
        const int q = t >> 7;           // 0..3 (wave-uniform) -> channel quarter
        const int p = t & 127;          // pooled output position
        const int l0 = 2 * p;
        for (int ccb = 0; ccb < 4; ++ccb) {
            const int cbase = q * 32 + ccb * 8;
            float a0[8], a1[8];
            #pragma unroll
            for (int cj = 0; cj < 8; ++cj) { a0[cj] = b2[cbase + cj]; a1[cj] = a0[cj]; }
            #pragma unroll 2
            for (int i = 0; i < 64; ++i) {
                const float* __restrict__ row = bufA + i * 256;
                float xw[6];
                #pragma unroll
                for (int j = 0; j < 6; ++j) {
                    int pos = l0 - 2 + j;
                    xw[j] = (pos >= 0 && pos < 256) ? row[pos] : 0.f;
                }
                #pragma unroll
                for (int cj = 0; cj < 8; ++cj) {
                    const float* __restrict__ wr = w2 + ((cbase + cj) * 64 + i) * 5;
                    #pragma unroll
                    for (int k = 0; k < 5; ++k) {
                        float wv = wr[k];                    // wave-uniform -> s_load
                        a0[cj] = fmaf(wv, xw[k],     a0[cj]);
                        a1[cj] = fmaf(wv, xw[k + 1], a1[cj]);
                    }
                }
            }
            #pragma unroll
            for (int cj = 0; cj < 8; ++cj)
                bufB[(cbase + cj) * 128 + p] = fmaxf(fmaxf(a0[cj], a1[cj]), 0.f);
        }
    }
    __syncthreads();

    // ---- conv3 (128->256, k=3, pad 1) + relu + maxpool2 -> p3[256][64] in bufA
    {
        const int q = t >> 6;           // 0..7 (wave id, uniform) -> channel eighth
        const int p = t & 63;           // pooled output position
        const int l0 = 2 * p;
        for (int ccb = 0; ccb < 4; ++ccb) {
            const int cbase = q * 32 + ccb * 8;
            float a0[8], a1[8];
            #pragma unroll
            for (int cj = 0; cj < 8; ++cj) { a0[cj] = b3[cbase + cj]; a1[cj] = a0[cj]; }
            #pragma unroll 2
            for (int i = 0; i < 128; ++i) {
                const float* __restrict__ row = bufB + i * 128;
                float xw[4];
                #pragma unroll
                for (int j = 0; j < 4; ++j) {
                    int pos = l0 - 1 + j;
                    xw[j] = (pos >= 0 && pos < 128) ? row[pos] : 0.f;
                }
                #pragma unroll
                for (int cj = 0; cj < 8; ++cj) {
                    const float* __restrict__ wr = w3 + ((cbase + cj) * 128 + i) * 3;
                    #pragma unroll
                    for (int k = 0; k < 3; ++k) {
                        float wv = wr[k];                    // wave-uniform -> s_load
                        a0[cj] = fmaf(wv, xw[k],     a0[cj]);
                        a1[cj] = fmaf(wv, xw[k + 1], a1[cj]);
                    }
                }
            }
            #pragma unroll
            for (int cj = 0; cj < 8; ++cj)
                bufA[(cbase + cj) * 64 + p] = fmaxf(fmaxf(a0[cj], a1[cj]), 0.f);
        }
    }
    __syncthreads();

    // ---- mean over length (64) -> feat[256] in xsp[0..255]
    if (t < 256) {
        const int c = t;
        float s = 0.f;
        #pragma unroll 8
        for (int j = 0; j < 64; ++j) {
            int jj = (j + c) & 63;       // rotate to avoid bank conflicts
            s += bufA[c * 64 + jj];
        }
        xsp[c] = s * (1.f / 64.f);
    }
    __syncthreads();

    // ---- fc (256->128) + relu -> h in xsp[256..383]
    {
        const int wave = t >> 6;
        const int lane = t & 63;
        for (int ow = 0; ow < 16; ++ow) {
            const int o = wave * 16 + ow;
            float s = 0.f;
            #pragma unroll
            for (int m = 0; m < 4; ++m) {
                int i = lane + 64 * m;
                s += fcw[o * 256 + i] * xsp[i];   // coalesced fcw, vector LDS feat
            }
            #pragma unroll
            for (int off = 32; off > 0; off >>= 1)
                s += __shfl_down(s, off);
            if (lane == 0) xsp[256 + o] = fmaxf(s + fcb[o], 0.f);
        }
    }
    __syncthreads();

    // ---- batchnorm -> z, and z^2 partials
    if (t < 128) {
        const int o = t;
        float hv = xsp[256 + o];
        float zv = gamma_[o] * (hv - bnm[o]) * (1.f / sqrtf(bnv[o] + 1e-5f)) + beta_[o];
        zout[(size_t)n * 128 + o] = zv;
        xsp[384 + o] = zv * zv;
    }
    __syncthreads();
    if (t < 64) {
        float s = xsp[384 + t] + xsp[384 + 64 + t];
        #pragma unroll
        for (int off = 32; off > 0; off >>= 1) s += __shfl_down(s, off);
        if (t == 0) sqout[n] = s;
    }
}

// ---- pairwise contrastive matrix: 64x64 output tile per block, 4x4 micro-tile.
// LDS tiles stored k-major with stride 65 (bank-conflict break): zT[k][r] = z[r0+r][k]
#define LDS_B_FLOATS (2 * 128 * 65)

__global__ __launch_bounds__(256, 2)
void pairwise(const float* __restrict__ z, const float* __restrict__ sq,
              const int* __restrict__ info, float* __restrict__ out)
{
    extern __shared__ float lds[];
    float* ziT = lds;            // [128][65]
    float* zjT = lds + 128 * 65; // [128][65]
    const int t = threadIdx.x;
    const int i0 = blockIdx.y * 64;
    const int j0 = blockIdx.x * 64;

    // transpose-load both tiles (float4 global reads, scalar LDS scatter)
    for (int f = t; f < 64 * 32; f += 256) {
        int r = f >> 5, kq = f & 31;
        float4 vi = ((const float4*)z)[(size_t)(i0 + r) * 32 + kq];
        float4 vj = ((const float4*)z)[(size_t)(j0 + r) * 32 + kq];
        int base = (4 * kq) * 65 + r;
        ziT[base]       = vi.x; ziT[base + 65]  = vi.y;
        ziT[base + 130] = vi.z; ziT[base + 195] = vi.w;
        zjT[base]       = vj.x; zjT[base + 65]  = vj.y;
        zjT[base + 130] = vj.z; zjT[base + 195] = vj.w;
    }
    __syncthreads();

    const int tx = t & 15, ty = t >> 4;
    float acc[4][4];
    #pragma unroll
    for (int a = 0; a < 4; ++a)
        #pragma unroll
        for (int b = 0; b < 4; ++b) acc[a][b] = 0.f;

    #pragma unroll 4
    for (int k = 0; k < 128; ++k) {
        float za[4], zb[4];
        #pragma unroll
        for (int a = 0; a < 4; ++a) za[a] = ziT[k * 65 + 4 * ty + a];
        #pragma unroll
        for (int b = 0; b < 4; ++b) zb[b] = zjT[k * 65 + 4 * tx + b];
        #pragma unroll
        for (int a = 0; a < 4; ++a)
            #pragma unroll
            for (int b = 0; b < 4; ++b)
                acc[a][b] = fmaf(za[a], zb[b], acc[a][b]);
    }

    // epilogue
    float sqi[4], sqj[4];
    int iw[4], ig[4], jw[4], jg[4];
    #pragma unroll
    for (int a = 0; a < 4; ++a) {
        int i = i0 + 4 * ty + a;
        sqi[a] = sq[i]; iw[a] = info[2 * i]; ig[a] = info[2 * i + 1];
    }
    #pragma unroll
    for (int b = 0; b < 4; ++b) {
        int j = j0 + 4 * tx + b;
        sqj[b] = sq[j]; jw[b] = info[2 * j]; jg[b] = info[2 * j + 1];
    }

    #pragma unroll
    for (int a = 0; a < 4; ++a) {
        int i = i0 + 4 * ty + a;
        float res[4];
        #pragma unroll
        for (int b = 0; b < 4; ++b) {
            int j = j0 + 4 * tx + b;
            float d2 = sqi[a] + sqj[b] - 2.f * acc[a][b];
            float r;
            if (i == j) {
                r = 0.f;
            } else {
                float d = sqrtf(fmaxf(d2, 0.f));
                bool y = (iw[a] == jw[b]) && (ig[a] == 1) && (jg[b] == 1);
                r = y ? d : fmaxf(1.f - d, 0.f);
            }
            res[b] = r;
        }
        *(float4*)(out + (size_t)i * 4096 + j0 + 4 * tx) =
            make_float4(res[0], res[1], res[2], res[3]);
    }
}

extern "C" void kernel_launch(void* const* d_in, const int* in_sizes, int n_in,
                              void* d_out, int out_size, void* d_ws, size_t ws_size,
                              hipStream_t stream)
{
    const float* samples = (const float*)d_in[0];
    const int*   info    = (const int*)d_in[1];
    const float* w1  = (const float*)d_in[2];
    const float* b1  = (const float*)d_in[3];
    const float* w2  = (const float*)d_in[4];
    const float* b2  = (const float*)d_in[5];
    const float* w3  = (const float*)d_in[6];
    const float* b3  = (const float*)d_in[7];
    const float* fcw = (const float*)d_in[8];
    const float* fcb = (const float*)d_in[9];
    const float* g   = (const float*)d_in[10];
    const float* be  = (const float*)d_in[11];
    const float* bm  = (const float*)d_in[12];
    const float* bv  = (const float*)d_in[13];
    float* out  = (float*)d_out;
    float* zws  = (float*)d_ws;                 // 4096*128 floats
    float* sqws = zws + (size_t)NS * 128;       // 4096 floats

    hipLaunchKernelGGL(cnn_fused, dim3(NS), dim3(512),
                       LDS_A_FLOATS * sizeof(float), stream,
                       samples, w1, b1, w2, b2, w3, b3, fcw, fcb,
                       g, be, bm, bv, zws, sqws);

    hipLaunchKernelGGL(pairwise, dim3(64, 64), dim3(256),
                       LDS_B_FLOATS * sizeof(float), stream,
                       zws, sqws, info, out);
}

// Round 2
// 5603.179 us; speedup vs baseline: 1.2527x; 1.2527x over previous
//
#include <hip/hip_runtime.h>
#include <math.h>

#define NS 4096

// LDS layout (floats):
//   xsp : [0, 640)                 padded input (612 used); later feat/h/zsq scratch
//   bufA: [640, 640+16640)         p1[64][260]  (halo +2 each side, stride 260)
//                                  later p3[256][64] (flat reuse)
//   bufB: [17280, 17280+16896)     p2[128][132] (halo +1 each side, stride 132)
#define LDS_A_FLOATS (640 + 64 * 260 + 128 * 132)

__global__ __launch_bounds__(512, 2)
void cnn_fused(const float* __restrict__ samples,
               const float* __restrict__ w1, const float* __restrict__ b1,
               const float* __restrict__ w2, const float* __restrict__ b2,
               const float* __restrict__ w3, const float* __restrict__ b3,
               const float* __restrict__ fcw, const float* __restrict__ fcb,
               const float* __restrict__ gamma_, const float* __restrict__ beta_,
               const float* __restrict__ bnm, const float* __restrict__ bnv,
               float* __restrict__ zout, float* __restrict__ sqout)
{
    extern __shared__ float lds[];
    float* xsp  = lds;
    float* bufA = lds + 640;                 // stride 260, value at pos p -> [p+2]
    float* bufB = lds + 640 + 64 * 260;      // stride 132, value at pos p -> [p+1]

    const int n = blockIdx.x;
    const int t = threadIdx.x;

    // ---- stage input with (49,50) zero padding: xsp[idx] = x[idx-49]
    for (int idx = t; idx < 612; idx += 512) {
        int src = idx - 49;
        xsp[idx] = (src >= 0 && src < 512) ? samples[n * 512 + src] : 0.f;
    }
    // ---- zero LDS halos (bufA rows: [0],[1],[258],[259]; bufB rows: [0],[129])
    if (t < 64) {
        float* r = bufA + t * 260;
        r[0] = 0.f; r[1] = 0.f; r[258] = 0.f; r[259] = 0.f;
    } else if (t < 192) {
        float* r = bufB + (t - 64) * 132;
        r[0] = 0.f; r[129] = 0.f;
    }
    __syncthreads();

    // ---- conv1 (1->64, k=100) + relu + maxpool2 -> p1[64][260-halo] in bufA
    {
        const int ch = t >> 8;          // wave-uniform
        const int p  = t & 255;         // pooled output position
        const int l0 = 2 * p;
        for (int ccb = 0; ccb < 4; ++ccb) {
            // force SGPR channel base -> all weight/bias reads become s_load
            const int cbase = __builtin_amdgcn_readfirstlane(ch * 32 + ccb * 8);
            float a0[8], a1[8];
            #pragma unroll
            for (int cj = 0; cj < 8; ++cj) { a0[cj] = b1[cbase + cj]; a1[cj] = a0[cj]; }
            float xa = xsp[l0];
            #pragma unroll 4
            for (int k = 0; k < 100; ++k) {
                float xb = xsp[l0 + k + 1];
                #pragma unroll
                for (int cj = 0; cj < 8; ++cj) {
                    float wv = w1[(cbase + cj) * 100 + k];   // scalar (SGPR-indexed)
                    a0[cj] = fmaf(wv, xa, a0[cj]);
                    a1[cj] = fmaf(wv, xb, a1[cj]);
                }
                xa = xb;
            }
            #pragma unroll
            for (int cj = 0; cj < 8; ++cj)
                bufA[(cbase + cj) * 260 + p + 2] = fmaxf(fmaxf(a0[cj], a1[cj]), 0.f);
        }
    }
    __syncthreads();

    // ---- conv2 (64->128, k=5, pad 2) + relu + maxpool2 -> p2 in bufB
    {
        const int q = t >> 7;           // wave-uniform
        const int p = t & 127;          // pooled output position
        const int l0 = 2 * p;
        for (int ccb = 0; ccb < 4; ++ccb) {
            const int cbase = __builtin_amdgcn_readfirstlane(q * 32 + ccb * 8);
            float a0[8], a1[8];
            #pragma unroll
            for (int cj = 0; cj < 8; ++cj) { a0[cj] = b2[cbase + cj]; a1[cj] = a0[cj]; }
            #pragma unroll 2
            for (int i = 0; i < 64; ++i) {
                const float* __restrict__ row = bufA + i * 260;
                // window pos l0-2 .. l0+3  ->  idx l0 .. l0+5 (halo shift +2), 8B aligned
                float2 u0 = *(const float2*)(row + l0);
                float2 u1 = *(const float2*)(row + l0 + 2);
                float2 u2 = *(const float2*)(row + l0 + 4);
                float xw0 = u0.x, xw1 = u0.y, xw2 = u1.x, xw3 = u1.y, xw4 = u2.x, xw5 = u2.y;
                #pragma unroll
                for (int cj = 0; cj < 8; ++cj) {
                    const float* __restrict__ wr = w2 + ((cbase + cj) * 64 + i) * 5;
                    float w0 = wr[0], w1v = wr[1], w2v = wr[2], w3v = wr[3], w4v = wr[4];
                    a0[cj] = fmaf(w0, xw0, a0[cj]);  a1[cj] = fmaf(w0, xw1, a1[cj]);
                    a0[cj] = fmaf(w1v, xw1, a0[cj]); a1[cj] = fmaf(w1v, xw2, a1[cj]);
                    a0[cj] = fmaf(w2v, xw2, a0[cj]); a1[cj] = fmaf(w2v, xw3, a1[cj]);
                    a0[cj] = fmaf(w3v, xw3, a0[cj]); a1[cj] = fmaf(w3v, xw4, a1[cj]);
                    a0[cj] = fmaf(w4v, xw4, a0[cj]); a1[cj] = fmaf(w4v, xw5, a1[cj]);
                }
            }
            #pragma unroll
            for (int cj = 0; cj < 8; ++cj)
                bufB[(cbase + cj) * 132 + p + 1] = fmaxf(fmaxf(a0[cj], a1[cj]), 0.f);
        }
    }
    __syncthreads();

    // ---- conv3 (128->256, k=3, pad 1) + relu + maxpool2 -> p3[256][64] in bufA (flat)
    {
        const int q = t >> 6;           // wave id, uniform
        const int p = t & 63;           // pooled output position
        const int l0 = 2 * p;
        for (int ccb = 0; ccb < 4; ++ccb) {
            const int cbase = __builtin_amdgcn_readfirstlane(q * 32 + ccb * 8);
            float a0[8], a1[8];
            #pragma unroll
            for (int cj = 0; cj < 8; ++cj) { a0[cj] = b3[cbase + cj]; a1[cj] = a0[cj]; }
            #pragma unroll 2
            for (int i = 0; i < 128; ++i) {
                const float* __restrict__ row = bufB + i * 132;
                // window pos l0-1 .. l0+2  ->  idx l0 .. l0+3 (halo shift +1), 8B aligned
                float2 u0 = *(const float2*)(row + l0);
                float2 u1 = *(const float2*)(row + l0 + 2);
                float xw0 = u0.x, xw1 = u0.y, xw2 = u1.x, xw3 = u1.y;
                #pragma unroll
                for (int cj = 0; cj < 8; ++cj) {
                    const float* __restrict__ wr = w3 + ((cbase + cj) * 128 + i) * 3;
                    float w0 = wr[0], w1v = wr[1], w2v = wr[2];
                    a0[cj] = fmaf(w0, xw0, a0[cj]);  a1[cj] = fmaf(w0, xw1, a1[cj]);
                    a0[cj] = fmaf(w1v, xw1, a0[cj]); a1[cj] = fmaf(w1v, xw2, a1[cj]);
                    a0[cj] = fmaf(w2v, xw2, a0[cj]); a1[cj] = fmaf(w2v, xw3, a1[cj]);
                }
            }
            #pragma unroll
            for (int cj = 0; cj < 8; ++cj)
                bufA[(cbase + cj) * 64 + p] = fmaxf(fmaxf(a0[cj], a1[cj]), 0.f);
        }
    }
    __syncthreads();

    // ---- mean over length (64) -> feat[256] in xsp[0..255]
    if (t < 256) {
        const int c = t;
        float s = 0.f;
        #pragma unroll 8
        for (int j = 0; j < 64; ++j) {
            int jj = (j + c) & 63;       // rotate to avoid bank conflicts
            s += bufA[c * 64 + jj];
        }
        xsp[c] = s * (1.f / 64.f);
    }
    __syncthreads();

    // ---- fc (256->128) + relu -> h in xsp[256..383]
    {
        const int wave = t >> 6;
        const int lane = t & 63;
        for (int ow = 0; ow < 16; ++ow) {
            const int o = wave * 16 + ow;
            float s = 0.f;
            #pragma unroll
            for (int m = 0; m < 4; ++m) {
                int i = lane + 64 * m;
                s += fcw[o * 256 + i] * xsp[i];
            }
            #pragma unroll
            for (int off = 32; off > 0; off >>= 1)
                s += __shfl_down(s, off);
            if (lane == 0) xsp[256 + o] = fmaxf(s + fcb[o], 0.f);
        }
    }
    __syncthreads();

    // ---- batchnorm -> z, and z^2 partials
    if (t < 128) {
        const int o = t;
        float hv = xsp[256 + o];
        float zv = gamma_[o] * (hv - bnm[o]) * (1.f / sqrtf(bnv[o] + 1e-5f)) + beta_[o];
        zout[(size_t)n * 128 + o] = zv;
        xsp[384 + o] = zv * zv;
    }
    __syncthreads();
    if (t < 64) {
        float s = xsp[384 + t] + xsp[384 + 64 + t];
        #pragma unroll
        for (int off = 32; off > 0; off >>= 1) s += __shfl_down(s, off);
        if (t == 0) sqout[n] = s;
    }
}

// ---- pairwise contrastive matrix: 64x64 output tile per block, 4x4 micro-tile.
#define LDS_B_FLOATS (2 * 128 * 65)

__global__ __launch_bounds__(256, 2)
void pairwise(const float* __restrict__ z, const float* __restrict__ sq,
              const int* __restrict__ info, float* __restrict__ out)
{
    extern __shared__ float lds[];
    float* ziT = lds;            // [128][65]
    float* zjT = lds + 128 * 65; // [128][65]
    const int t = threadIdx.x;
    const int i0 = blockIdx.y * 64;
    const int j0 = blockIdx.x * 64;

    for (int f = t; f < 64 * 32; f += 256) {
        int r = f >> 5, kq = f & 31;
        float4 vi = ((const float4*)z)[(size_t)(i0 + r) * 32 + kq];
        float4 vj = ((const float4*)z)[(size_t)(j0 + r) * 32 + kq];
        int base = (4 * kq) * 65 + r;
        ziT[base]       = vi.x; ziT[base + 65]  = vi.y;
        ziT[base + 130] = vi.z; ziT[base + 195] = vi.w;
        zjT[base]       = vj.x; zjT[base + 65]  = vj.y;
        zjT[base + 130] = vj.z; zjT[base + 195] = vj.w;
    }
    __syncthreads();

    const int tx = t & 15, ty = t >> 4;
    float acc[4][4];
    #pragma unroll
    for (int a = 0; a < 4; ++a)
        #pragma unroll
        for (int b = 0; b < 4; ++b) acc[a][b] = 0.f;

    #pragma unroll 4
    for (int k = 0; k < 128; ++k) {
        float za[4], zb[4];
        #pragma unroll
        for (int a = 0; a < 4; ++a) za[a] = ziT[k * 65 + 4 * ty + a];
        #pragma unroll
        for (int b = 0; b < 4; ++b) zb[b] = zjT[k * 65 + 4 * tx + b];
        #pragma unroll
        for (int a = 0; a < 4; ++a)
            #pragma unroll
            for (int b = 0; b < 4; ++b)
                acc[a][b] = fmaf(za[a], zb[b], acc[a][b]);
    }

    float sqi[4], sqj[4];
    int iw[4], ig[4], jw[4], jg[4];
    #pragma unroll
    for (int a = 0; a < 4; ++a) {
        int i = i0 + 4 * ty + a;
        sqi[a] = sq[i]; iw[a] = info[2 * i]; ig[a] = info[2 * i + 1];
    }
    #pragma unroll
    for (int b = 0; b < 4; ++b) {
        int j = j0 + 4 * tx + b;
        sqj[b] = sq[j]; jw[b] = info[2 * j]; jg[b] = info[2 * j + 1];
    }

    #pragma unroll
    for (int a = 0; a < 4; ++a) {
        int i = i0 + 4 * ty + a;
        float res[4];
        #pragma unroll
        for (int b = 0; b < 4; ++b) {
            int j = j0 + 4 * tx + b;
            float d2 = sqi[a] + sqj[b] - 2.f * acc[a][b];
            float r;
            if (i == j) {
                r = 0.f;
            } else {
                float d = sqrtf(fmaxf(d2, 0.f));
                bool y = (iw[a] == jw[b]) && (ig[a] == 1) && (jg[b] == 1);
                r = y ? d : fmaxf(1.f - d, 0.f);
            }
            res[b] = r;
        }
        *(float4*)(out + (size_t)i * 4096 + j0 + 4 * tx) =
            make_float4(res[0], res[1], res[2], res[3]);
    }
}

extern "C" void kernel_launch(void* const* d_in, const int* in_sizes, int n_in,
                              void* d_out, int out_size, void* d_ws, size_t ws_size,
                              hipStream_t stream)
{
    const float* samples = (const float*)d_in[0];
    const int*   info    = (const int*)d_in[1];
    const float* w1  = (const float*)d_in[2];
    const float* b1  = (const float*)d_in[3];
    const float* w2  = (const float*)d_in[4];
    const float* b2  = (const float*)d_in[5];
    const float* w3  = (const float*)d_in[6];
    const float* b3  = (const float*)d_in[7];
    const float* fcw = (const float*)d_in[8];
    const float* fcb = (const float*)d_in[9];
    const float* g   = (const float*)d_in[10];
    const float* be  = (const float*)d_in[11];
    const float* bm  = (const float*)d_in[12];
    const float* bv  = (const float*)d_in[13];
    float* out  = (float*)d_out;
    float* zws  = (float*)d_ws;                 // 4096*128 floats
    float* sqws = zws + (size_t)NS * 128;       // 4096 floats

    hipLaunchKernelGGL(cnn_fused, dim3(NS), dim3(512),
                       LDS_A_FLOATS * sizeof(float), stream,
                       samples, w1, b1, w2, b2, w3, b3, fcw, fcb,
                       g, be, bm, bv, zws, sqws);

    hipLaunchKernelGGL(pairwise, dim3(64, 64), dim3(256),
                       LDS_B_FLOATS * sizeof(float), stream,
                       zws, sqws, info, out);
}

// Round 3
// 714.978 us; speedup vs baseline: 9.8168x; 7.8369x over previous
//
#include <hip/hip_runtime.h>
#include <math.h>

#define NS 4096

typedef _Float16 half8 __attribute__((ext_vector_type(8)));
typedef _Float16 half2v __attribute__((ext_vector_type(2)));
typedef float floatx16 __attribute__((ext_vector_type(16)));

// ---------------- LDS layout (float offsets), main kernel ----------------
// xc  : 8 shift-copies of f16 padded input, stride 648 f16  -> 2592 floats
// p1T : [260 pos][80 f16]  (64 ch used, stride 80 for 16B-aligned conflict-free b128)
// p2T : [130 pos][144 f16] (128 ch used)
// scr : xpad32 f32[640] during staging; later feat[256]@0, h[128]@256, zsq[128]@384
// bias arrays f32
#define XC_OFF      0
#define XC_STRIDE   648
#define P1T_OFF     2592
#define P1T_STRIDE  80
#define P2T_OFF     12992
#define P2T_STRIDE  144
#define SCR_OFF     22352
#define B2_OFF      22992
#define B3_OFF      23120
#define B1_OFF      23376
#define LDS_MAIN_FLOATS 23440   // 93.76 KB

// ---------------- weight prep: f32 -> f16 MFMA-friendly layouts ----------------
// w1p[64 m][128 k]   (k<100 real, else 0)
// w2p[5 dk][128 m][64 i]
// w3p[3 dk][256 m][128 i]
__global__ void prep_weights(const float* __restrict__ w1,
                             const float* __restrict__ w2,
                             const float* __restrict__ w3,
                             _Float16* __restrict__ w1p,
                             _Float16* __restrict__ w2p,
                             _Float16* __restrict__ w3p)
{
    int gid = blockIdx.x * 256 + threadIdx.x;
    if (gid < 8192) {
        int m = gid >> 7, k = gid & 127;
        w1p[gid] = (k < 100) ? (_Float16)w1[m * 100 + k] : (_Float16)0.f;
    } else if (gid < 49152) {
        int r = gid - 8192;
        int dk = r >> 13, rem = r & 8191;
        int m = rem >> 6, i = rem & 63;
        w2p[r] = (_Float16)w2[(m * 64 + i) * 5 + dk];
    } else if (gid < 147456) {
        int r = gid - 49152;
        int dk = r >> 15, rem = r & 32767;
        int m = rem >> 7, i = rem & 127;
        w3p[r] = (_Float16)w3[(m * 128 + i) * 3 + dk];
    }
}

// C/D 32x32 layout: col = lane&31, row = (reg&3) + 8*(reg>>2) + 4*(lane>>5)
// A/B layout: m|n = lane&31, k = (lane>>5)*8 + j

__global__ __launch_bounds__(512, 1)
void cnn_fused(const float* __restrict__ samples,
               const _Float16* __restrict__ w1p,
               const _Float16* __restrict__ w2p,
               const _Float16* __restrict__ w3p,
               const float* __restrict__ b1, const float* __restrict__ b2,
               const float* __restrict__ b3,
               const float* __restrict__ fcw, const float* __restrict__ fcb,
               const float* __restrict__ gamma_, const float* __restrict__ beta_,
               const float* __restrict__ bnm, const float* __restrict__ bnv,
               float* __restrict__ zout, float* __restrict__ sqout)
{
    extern __shared__ float lds[];
    _Float16* xc  = (_Float16*)(lds + XC_OFF);
    _Float16* p1T = (_Float16*)(lds + P1T_OFF);
    _Float16* p2T = (_Float16*)(lds + P2T_OFF);
    float* scr = lds + SCR_OFF;

    const int n    = blockIdx.x;
    const int t    = threadIdx.x;
    const int lane = t & 63;
    const int wave = t >> 6;
    const int g    = lane >> 5;      // half-wave id (k-group)
    const int col  = lane & 31;      // M/N index within tile

    // ---- stage padded input f32: scr[i] = x[i-49], zeros outside
    for (int i = t; i < 640; i += 512) {
        int u = i - 49;
        scr[i] = (u >= 0 && u < 512) ? samples[n * 512 + u] : 0.f;
    }
    // ---- stage biases
    if (t < 64)                 lds[B1_OFF + t] = b1[t];
    if (t >= 64 && t < 192)     lds[B2_OFF + (t - 64)] = b2[t - 64];
    if (t >= 192 && t < 448)    lds[B3_OFF + (t - 192)] = b3[t - 192];
    // ---- zero halos: p1T rows {0,1,258,259}, p2T rows {0,129}
    if (t < 160) {
        int r4 = t / 40, c4 = t % 40;
        int row = (r4 < 2) ? r4 : (256 + r4);
        ((float*)(p1T + row * P1T_STRIDE))[c4] = 0.f;
    } else if (t < 304) {
        int i2 = t - 160;
        int row = (i2 < 72) ? 0 : 129;
        int c4 = (i2 < 72) ? i2 : (i2 - 72);
        ((float*)(p2T + row * P2T_STRIDE))[c4] = 0.f;
    }
    __syncthreads();

    // ---- build 8 shifted f16 copies: xc[c][u] = xpad[u+c] (16B-alignable B reads)
    for (int i = t; i < 8 * XC_STRIDE; i += 512) {
        int c = i / XC_STRIDE, u = i % XC_STRIDE;
        int src = u + c;
        xc[i] = (_Float16)((src < 640) ? scr[src] : 0.f);
    }
    __syncthreads();

    // ===================== conv1: GEMM M=64, N=512, K=128 (pad) =====================
    {
        const int mt = wave & 1;
        const int ntbase = (wave >> 1) * 4;
        half8 A[8];
        #pragma unroll
        for (int kb = 0; kb < 8; ++kb)
            A[kb] = *(const half8*)(w1p + (mt * 32 + col) * 128 + kb * 16 + g * 8);
        for (int s = 0; s < 4; ++s) {
            const int nt = ntbase + s;
            const int nn = nt * 32 + col;
            const int c  = nn & 7;
            const _Float16* xcp = xc + c * XC_STRIDE + (nn - c) + g * 8;
            floatx16 acc;
            #pragma unroll
            for (int r = 0; r < 16; ++r)
                acc[r] = lds[B1_OFF + mt * 32 + (r & 3) + 8 * (r >> 2) + 4 * g];
            #pragma unroll
            for (int kb = 0; kb < 8; ++kb) {
                half8 B = *(const half8*)(xcp + kb * 16);
                acc = __builtin_amdgcn_mfma_f32_32x32x16_f16(A[kb], B, acc, 0, 0, 0);
            }
            // epilogue: relu + maxpool(pairs of cols) + transposed store to p1T
            float vm[16];
            #pragma unroll
            for (int r = 0; r < 16; ++r) {
                float v = fmaxf(acc[r], 0.f);
                vm[r] = fmaxf(v, __shfl_xor(v, 1));
            }
            if ((lane & 1) == 0) {
                int P = 2 + nt * 16 + (col >> 1);
                _Float16* dst = p1T + P * P1T_STRIDE + mt * 32 + 4 * g;
                #pragma unroll
                for (int rq = 0; rq < 4; ++rq) {
                    half2v p0, p1;
                    p0[0] = (_Float16)vm[4 * rq];     p0[1] = (_Float16)vm[4 * rq + 1];
                    p1[0] = (_Float16)vm[4 * rq + 2]; p1[1] = (_Float16)vm[4 * rq + 3];
                    *(half2v*)(dst + 8 * rq)     = p0;
                    *(half2v*)(dst + 8 * rq + 2) = p1;
                }
            }
        }
    }
    __syncthreads();

    // ===================== conv2: M=128, N=256, K=5x64 =====================
    {
        const int mt = wave & 3;
        const int ntbase = (wave >> 2) * 4;
        half8 A[20];
        #pragma unroll
        for (int dk = 0; dk < 5; ++dk)
            #pragma unroll
            for (int kb = 0; kb < 4; ++kb)
                A[dk * 4 + kb] = *(const half8*)(w2p + (dk * 128 + mt * 32 + col) * 64 + kb * 16 + g * 8);
        for (int s = 0; s < 4; ++s) {
            const int nt = ntbase + s;
            const int pos = nt * 32 + col;
            floatx16 acc;
            #pragma unroll
            for (int r = 0; r < 16; ++r)
                acc[r] = lds[B2_OFF + mt * 32 + (r & 3) + 8 * (r >> 2) + 4 * g];
            #pragma unroll
            for (int dk = 0; dk < 5; ++dk) {
                const _Float16* bp = p1T + (pos + dk) * P1T_STRIDE + g * 8;
                #pragma unroll
                for (int kb = 0; kb < 4; ++kb) {
                    half8 B = *(const half8*)(bp + kb * 16);
                    acc = __builtin_amdgcn_mfma_f32_32x32x16_f16(A[dk * 4 + kb], B, acc, 0, 0, 0);
                }
            }
            float vm[16];
            #pragma unroll
            for (int r = 0; r < 16; ++r) {
                float v = fmaxf(acc[r], 0.f);
                vm[r] = fmaxf(v, __shfl_xor(v, 1));
            }
            if ((lane & 1) == 0) {
                int P = 1 + nt * 16 + (col >> 1);
                _Float16* dst = p2T + P * P2T_STRIDE + mt * 32 + 4 * g;
                #pragma unroll
                for (int rq = 0; rq < 4; ++rq) {
                    half2v p0, p1;
                    p0[0] = (_Float16)vm[4 * rq];     p0[1] = (_Float16)vm[4 * rq + 1];
                    p1[0] = (_Float16)vm[4 * rq + 2]; p1[1] = (_Float16)vm[4 * rq + 3];
                    *(half2v*)(dst + 8 * rq)     = p0;
                    *(half2v*)(dst + 8 * rq + 2) = p1;
                }
            }
        }
    }
    __syncthreads();

    // ===================== conv3: M=256, N=128, K=3x128; fused pool+mean =====================
    {
        const int mt = wave;     // 8 mtiles, one per wave -> exclusive row ownership
        half8 A[24];
        #pragma unroll
        for (int dk = 0; dk < 3; ++dk)
            #pragma unroll
            for (int kb = 0; kb < 8; ++kb)
                A[dk * 8 + kb] = *(const half8*)(w3p + (dk * 256 + mt * 32 + col) * 128 + kb * 16 + g * 8);
        float racc[16];
        #pragma unroll
        for (int r = 0; r < 16; ++r) racc[r] = 0.f;
        for (int nt = 0; nt < 4; ++nt) {
            const int pos = nt * 32 + col;
            floatx16 acc;
            #pragma unroll
            for (int r = 0; r < 16; ++r)
                acc[r] = lds[B3_OFF + mt * 32 + (r & 3) + 8 * (r >> 2) + 4 * g];
            #pragma unroll
            for (int dk = 0; dk < 3; ++dk) {
                const _Float16* bp = p2T + (pos + dk) * P2T_STRIDE + g * 8;
                #pragma unroll
                for (int kb = 0; kb < 8; ++kb) {
                    half8 B = *(const half8*)(bp + kb * 16);
                    acc = __builtin_amdgcn_mfma_f32_32x32x16_f16(A[dk * 8 + kb], B, acc, 0, 0, 0);
                }
            }
            #pragma unroll
            for (int r = 0; r < 16; ++r) {
                float v = fmaxf(acc[r], 0.f);
                racc[r] += fmaxf(v, __shfl_xor(v, 1));   // pooled max (dup in pair lanes)
            }
        }
        // sum over the 16 same-parity columns (= 16 pooled pairs per parity; dup-safe)
        #pragma unroll
        for (int r = 0; r < 16; ++r) {
            float s = racc[r];
            s += __shfl_xor(s, 2);
            s += __shfl_xor(s, 4);
            s += __shfl_xor(s, 8);
            s += __shfl_xor(s, 16);
            racc[r] = s;
        }
        if (col == 0) {
            #pragma unroll
            for (int r = 0; r < 16; ++r)
                scr[mt * 32 + (r & 3) + 8 * (r >> 2) + 4 * g] = racc[r] * (1.f / 64.f);
        }
    }
    __syncthreads();

    // ---- fc (256->128) + relu -> h in scr[256..383]
    {
        for (int ow = 0; ow < 16; ++ow) {
            const int o = wave * 16 + ow;
            float s = 0.f;
            #pragma unroll
            for (int m = 0; m < 4; ++m) {
                int i = lane + 64 * m;
                s += fcw[o * 256 + i] * scr[i];
            }
            #pragma unroll
            for (int off = 32; off > 0; off >>= 1)
                s += __shfl_down(s, off);
            if (lane == 0) scr[256 + o] = fmaxf(s + fcb[o], 0.f);
        }
    }
    __syncthreads();

    // ---- batchnorm -> z, and z^2 partials
    if (t < 128) {
        const int o = t;
        float hv = scr[256 + o];
        float zv = gamma_[o] * (hv - bnm[o]) * (1.f / sqrtf(bnv[o] + 1e-5f)) + beta_[o];
        zout[(size_t)n * 128 + o] = zv;
        scr[384 + o] = zv * zv;
    }
    __syncthreads();
    if (t < 64) {
        float s = scr[384 + t] + scr[384 + 64 + t];
        #pragma unroll
        for (int off = 32; off > 0; off >>= 1) s += __shfl_down(s, off);
        if (t == 0) sqout[n] = s;
    }
}

// ---- pairwise contrastive matrix: 64x64 tile per block, 4x4 micro-tile.
#define LDS_B_FLOATS (2 * 128 * 65)

__global__ __launch_bounds__(256, 2)
void pairwise(const float* __restrict__ z, const float* __restrict__ sq,
              const int* __restrict__ info, float* __restrict__ out)
{
    extern __shared__ float lds[];
    float* ziT = lds;            // [128][65]
    float* zjT = lds + 128 * 65; // [128][65]
    const int t = threadIdx.x;
    const int i0 = blockIdx.y * 64;
    const int j0 = blockIdx.x * 64;

    for (int f = t; f < 64 * 32; f += 256) {
        int r = f >> 5, kq = f & 31;
        float4 vi = ((const float4*)z)[(size_t)(i0 + r) * 32 + kq];
        float4 vj = ((const float4*)z)[(size_t)(j0 + r) * 32 + kq];
        int base = (4 * kq) * 65 + r;
        ziT[base]       = vi.x; ziT[base + 65]  = vi.y;
        ziT[base + 130] = vi.z; ziT[base + 195] = vi.w;
        zjT[base]       = vj.x; zjT[base + 65]  = vj.y;
        zjT[base + 130] = vj.z; zjT[base + 195] = vj.w;
    }
    __syncthreads();

    const int tx = t & 15, ty = t >> 4;
    float acc[4][4];
    #pragma unroll
    for (int a = 0; a < 4; ++a)
        #pragma unroll
        for (int b = 0; b < 4; ++b) acc[a][b] = 0.f;

    #pragma unroll 4
    for (int k = 0; k < 128; ++k) {
        float za[4], zb[4];
        #pragma unroll
        for (int a = 0; a < 4; ++a) za[a] = ziT[k * 65 + 4 * ty + a];
        #pragma unroll
        for (int b = 0; b < 4; ++b) zb[b] = zjT[k * 65 + 4 * tx + b];
        #pragma unroll
        for (int a = 0; a < 4; ++a)
            #pragma unroll
            for (int b = 0; b < 4; ++b)
                acc[a][b] = fmaf(za[a], zb[b], acc[a][b]);
    }

    float sqi[4], sqj[4];
    int iw[4], ig[4], jw[4], jg[4];
    #pragma unroll
    for (int a = 0; a < 4; ++a) {
        int i = i0 + 4 * ty + a;
        sqi[a] = sq[i]; iw[a] = info[2 * i]; ig[a] = info[2 * i + 1];
    }
    #pragma unroll
    for (int b = 0; b < 4; ++b) {
        int j = j0 + 4 * tx + b;
        sqj[b] = sq[j]; jw[b] = info[2 * j]; jg[b] = info[2 * j + 1];
    }

    #pragma unroll
    for (int a = 0; a < 4; ++a) {
        int i = i0 + 4 * ty + a;
        float res[4];
        #pragma unroll
        for (int b = 0; b < 4; ++b) {
            int j = j0 + 4 * tx + b;
            float d2 = sqi[a] + sqj[b] - 2.f * acc[a][b];
            float r;
            if (i == j) {
                r = 0.f;
            } else {
                float d = sqrtf(fmaxf(d2, 0.f));
                bool y = (iw[a] == jw[b]) && (ig[a] == 1) && (jg[b] == 1);
                r = y ? d : fmaxf(1.f - d, 0.f);
            }
            res[b] = r;
        }
        *(float4*)(out + (size_t)i * 4096 + j0 + 4 * tx) =
            make_float4(res[0], res[1], res[2], res[3]);
    }
}

extern "C" void kernel_launch(void* const* d_in, const int* in_sizes, int n_in,
                              void* d_out, int out_size, void* d_ws, size_t ws_size,
                              hipStream_t stream)
{
    const float* samples = (const float*)d_in[0];
    const int*   info    = (const int*)d_in[1];
    const float* w1  = (const float*)d_in[2];
    const float* b1  = (const float*)d_in[3];
    const float* w2  = (const float*)d_in[4];
    const float* b2  = (const float*)d_in[5];
    const float* w3  = (const float*)d_in[6];
    const float* b3  = (const float*)d_in[7];
    const float* fcw = (const float*)d_in[8];
    const float* fcb = (const float*)d_in[9];
    const float* g   = (const float*)d_in[10];
    const float* be  = (const float*)d_in[11];
    const float* bm  = (const float*)d_in[12];
    const float* bv  = (const float*)d_in[13];
    float* out  = (float*)d_out;

    float* zws  = (float*)d_ws;                    // 4096*128 f32
    float* sqws = zws + (size_t)NS * 128;          // 4096 f32
    _Float16* wp  = (_Float16*)(sqws + NS);        // 16B-aligned (offset 2,113,536 B)
    _Float16* w1p = wp;                            // 8192 f16
    _Float16* w2p = wp + 8192;                     // 40960 f16
    _Float16* w3p = wp + 49152;                    // 98304 f16

    hipLaunchKernelGGL(prep_weights, dim3(576), dim3(256), 0, stream,
                       w1, w2, w3, w1p, w2p, w3p);

    hipLaunchKernelGGL(cnn_fused, dim3(NS), dim3(512),
                       LDS_MAIN_FLOATS * sizeof(float), stream,
                       samples, w1p, w2p, w3p, b1, b2, b3, fcw, fcb,
                       g, be, bm, bv, zws, sqws);

    hipLaunchKernelGGL(pairwise, dim3(64, 64), dim3(256),
                       LDS_B_FLOATS * sizeof(float), stream,
                       zws, sqws, info, out);
}